// Round 1
// 611.976 us; speedup vs baseline: 1.0055x; 1.0055x over previous
//
#include <hip/hip_runtime.h>

#define BATCH   16384
#define KK      26
#define VDIM    128
#define NWORDS  100000

// DPP-shifted copy of x (0-fill out of row), added by caller. VALU-speed
// cross-lane: row_shr:n = 0x110|n, row_bcast15 = 0x142.
template <int CTRL>
__device__ __forceinline__ float dpp_mov(float x) {
    int xi = __builtin_bit_cast(int, x);
    int yi = __builtin_amdgcn_update_dpp(0, xi, CTRL, 0xF, 0xF, true);
    return __builtin_bit_cast(float, yi);
}

// ---------------------------------------------------------------------------
// Kernel 1: transpose O [VDIM, NWORDS] -> Ot [NWORDS, VDIM]
// Read float4 rows of O, scatter into tile[w][v] (pad 129 -> ~2-way conflicts,
// free on wave64); write phase is ds_read_b128 + coalesced float4 stores.
// Memory-bound at ~102 MB total; leave structure alone.
// ---------------------------------------------------------------------------
__global__ __launch_bounds__(256) void transpose_O(const float* __restrict__ O,
                                                   float* __restrict__ Ot) {
    __shared__ float tile[32][129];  // [w][v], pad breaks conflicts
    const int wbase = blockIdx.x * 32;
    const int t = threadIdx.x;

    #pragma unroll
    for (int i = 0; i < 4; ++i) {
        int idx = i * 256 + t;          // 0..1023
        int v = idx >> 3;               // 0..127
        int w4 = (idx & 7) * 4;         // 0,4,..,28
        float4 r = *(const float4*)&O[(size_t)v * NWORDS + wbase + w4];
        tile[w4 + 0][v] = r.x;
        tile[w4 + 1][v] = r.y;
        tile[w4 + 2][v] = r.z;
        tile[w4 + 3][v] = r.w;
    }
    __syncthreads();

    #pragma unroll
    for (int i = 0; i < 4; ++i) {
        int idx = i * 256 + t;
        int w = idx >> 5;               // 0..31
        int v = (idx & 31) * 4;         // 0,4,..,124
        *(float4*)&Ot[(size_t)(wbase + w) * VDIM + v] =
            *(const float4*)&tile[w][v];
    }
}

// ---------------------------------------------------------------------------
// Kernel 2: gather-dot, 2 batches per block (8192 blocks). 8 groups of 32
// lanes; group g handles k = g, g+8, g+16, g+24 for BOTH b's. All id loads
// and all 8 Ot row gathers are issued unconditionally up front (invalid k
// clamps to row 0, which is L1-hot) -> 10 outstanding loads per thread
// across the dependent chain, no exec-mask branches around the gathers.
// Then DPP-based 32-lane reductions (pure VALU, no LDS, no syncthreads).
// ---------------------------------------------------------------------------
__global__ __launch_bounds__(256) void gather_dot(const int* __restrict__ doc_ids,
                                                  const int* __restrict__ tn_ids,
                                                  const float* __restrict__ D,
                                                  const float* __restrict__ Ot,
                                                  float* __restrict__ out) {
    const int b0 = blockIdx.x * 2;
    const int t = threadIdx.x;
    const int g = t >> 5;               // 0..7
    const int l = t & 31;

    // Uniform doc ids -> scalar loads; issue both D row gathers immediately.
    const int doc0 = doc_ids[b0];
    const int doc1 = doc_ids[b0 + 1];
    const float4 dv0 = *(const float4*)&D[(size_t)doc0 * VDIM + l * 4];
    const float4 dv1 = *(const float4*)&D[(size_t)doc1 * VDIM + l * 4];

    // All 8 word ids (2 b's x 4 k-slots). Clamp invalid slots to word 0.
    int word[2][4];
    #pragma unroll
    for (int j = 0; j < 4; ++j) {
        const int k = g + 8 * j;
        const bool ok = (k < KK);
        word[0][j] = ok ? tn_ids[b0 * KK + k] : 0;
        word[1][j] = ok ? tn_ids[(b0 + 1) * KK + k] : 0;
    }

    // All 8 row gathers issued back-to-back (no branches -> max MLP).
    float4 wv[2][4];
    #pragma unroll
    for (int m = 0; m < 2; ++m)
        #pragma unroll
        for (int j = 0; j < 4; ++j)
            wv[m][j] = *(const float4*)&Ot[(size_t)word[m][j] * VDIM + l * 4];

    #pragma unroll
    for (int m = 0; m < 2; ++m) {
        const float4 dv = m ? dv1 : dv0;
        const int base = (b0 + m) * KK;
        #pragma unroll
        for (int j = 0; j < 4; ++j) {
            const int k = g + 8 * j;
            float p = dv.x * wv[m][j].x + dv.y * wv[m][j].y
                    + dv.z * wv[m][j].z + dv.w * wv[m][j].w;
            p += dpp_mov<0x111>(p);     // row_shr:1
            p += dpp_mov<0x112>(p);     // row_shr:2
            p += dpp_mov<0x114>(p);     // row_shr:4
            p += dpp_mov<0x118>(p);     // row_shr:8  -> lane15/31 hold row sums
            p += dpp_mov<0x142>(p);     // row_bcast15 -> lane31 holds 32-lane sum
            if (l == 31 && k < KK) out[base + k] = p;
        }
    }
}

// ---------------------------------------------------------------------------
// Fallback (only if ws_size < 51.2 MB): direct strided column gather of O.
// ---------------------------------------------------------------------------
__global__ __launch_bounds__(256) void gather_dot_direct(const int* __restrict__ doc_ids,
                                                         const int* __restrict__ tn_ids,
                                                         const float* __restrict__ D,
                                                         const float* __restrict__ O,
                                                         float* __restrict__ out) {
    __shared__ float d_s[VDIM];
    const int b = blockIdx.x;

    if (threadIdx.x < VDIM) {
        const int doc = doc_ids[b];
        d_s[threadIdx.x] = D[(size_t)doc * VDIM + threadIdx.x];
    }
    __syncthreads();

    const int wave = threadIdx.x >> 6;
    const int lane = threadIdx.x & 63;
    const int v0 = lane * 2;
    const float2 dv = *(const float2*)&d_s[v0];

    for (int k = wave; k < KK; k += 4) {
        const int word = tn_ids[b * KK + k];
        float p = dv.x * O[(size_t)v0 * NWORDS + word]
                + dv.y * O[(size_t)(v0 + 1) * NWORDS + word];
        #pragma unroll
        for (int off = 32; off > 0; off >>= 1)
            p += __shfl_down(p, off);
        if (lane == 0) out[b * KK + k] = p;
    }
}

extern "C" void kernel_launch(void* const* d_in, const int* in_sizes, int n_in,
                              void* d_out, int out_size, void* d_ws, size_t ws_size,
                              hipStream_t stream) {
    // setup_inputs order: context_ids, doc_ids, target_noise_ids, D, O
    const int*   doc_ids = (const int*)d_in[1];
    const int*   tn_ids  = (const int*)d_in[2];
    const float* D       = (const float*)d_in[3];
    const float* O       = (const float*)d_in[4];
    float*       out     = (float*)d_out;

    const size_t ot_bytes = (size_t)NWORDS * VDIM * sizeof(float);

    if (ws_size >= ot_bytes) {
        float* Ot = (float*)d_ws;
        transpose_O<<<NWORDS / 32, 256, 0, stream>>>(O, Ot);
        gather_dot<<<BATCH / 2, 256, 0, stream>>>(doc_ids, tn_ids, D, Ot, out);
    } else {
        gather_dot_direct<<<BATCH, 256, 0, stream>>>(doc_ids, tn_ids, D, O, out);
    }
}